// Round 5
// baseline (284.293 us; speedup 1.0000x reference)
//
#include <hip/hip_runtime.h>
#include <hip/hip_bf16.h>

// Problem constants
#define BATCH 2
#define SEQ   2048
#define EMBD  1024
#define NHEAD 16
#define HDIM  64
#define QKV3  (3 * EMBD)   // 3072

typedef __attribute__((ext_vector_type(8))) __bf16 bf16x8;
typedef __attribute__((ext_vector_type(4))) __bf16 bf16x4;
typedef __attribute__((ext_vector_type(4))) float f32x4;

// ---------------------------------------------------------------------------
// fp32 -> bf16 elementwise cast (8 elems/thread)
// ---------------------------------------------------------------------------
__global__ __launch_bounds__(256) void cast_f32_bf16(
    const float* __restrict__ in, __bf16* __restrict__ out)
{
    int i = (blockIdx.x * 256 + threadIdx.x) * 8;
    float4 a = *(const float4*)&in[i];
    float4 b = *(const float4*)&in[i + 4];
    bf16x8 o;
    o[0] = (__bf16)a.x; o[1] = (__bf16)a.y; o[2] = (__bf16)a.z; o[3] = (__bf16)a.w;
    o[4] = (__bf16)b.x; o[5] = (__bf16)b.y; o[6] = (__bf16)b.z; o[7] = (__bf16)b.w;
    *(bf16x8*)&out[i] = o;
}

// ---------------------------------------------------------------------------
// fp32 [K,N] -> bf16 [N,K] transpose+cast, 64x64 LDS tile, 256 threads
// ---------------------------------------------------------------------------
__global__ __launch_bounds__(256) void transpose_cast_bf16(
    const float* __restrict__ in, __bf16* __restrict__ out, int K, int N)
{
    __shared__ float t[64][65];
    const int k0 = blockIdx.y * 64, n0 = blockIdx.x * 64;
    const int tid = threadIdx.x;
    #pragma unroll
    for (int p = 0; p < 4; p++) {
        int kr = p * 16 + (tid >> 4);
        int c4 = (tid & 15) * 4;
        float4 v = *(const float4*)&in[(size_t)(k0 + kr) * N + n0 + c4];
        t[kr][c4] = v.x; t[kr][c4 + 1] = v.y; t[kr][c4 + 2] = v.z; t[kr][c4 + 3] = v.w;
    }
    __syncthreads();
    #pragma unroll
    for (int p = 0; p < 4; p++) {
        int nr = p * 16 + (tid >> 4);
        int k4 = (tid & 15) * 4;
        bf16x4 o;
        o[0] = (__bf16)t[k4 + 0][nr];
        o[1] = (__bf16)t[k4 + 1][nr];
        o[2] = (__bf16)t[k4 + 2][nr];
        o[3] = (__bf16)t[k4 + 3][nr];
        *(bf16x4*)&out[(size_t)(n0 + nr) * K + k0 + k4] = o;
    }
}

// ---------------------------------------------------------------------------
// bf16 V-transpose: qkv V region [k][d] per (b,h) -> vt[bh][d][k]
// grid: (SEQ/64, BATCH*NHEAD), 256 threads, 64x64 bf16 tile.
// ---------------------------------------------------------------------------
__global__ __launch_bounds__(256) void transpose_v_bf16(
    const __bf16* __restrict__ qkv, __bf16* __restrict__ vt)
{
    __shared__ __bf16 t[64][72];
    const int k0 = blockIdx.x * 64;
    const int bh = blockIdx.y;
    const int b = bh >> 4, h = bh & 15;
    const size_t base = (size_t)b * SEQ * QKV3 + 2 * EMBD + h * HDIM;
    const int tid = threadIdx.x;
    #pragma unroll
    for (int it = 0; it < 2; it++) {
        int flat = it * 256 + tid;      // 0..511
        int kr = flat >> 3;             // 0..63
        int d0 = (flat & 7) * 8;
        bf16x8 v = *(const bf16x8*)&qkv[base + (size_t)(k0 + kr) * QKV3 + d0];
        #pragma unroll
        for (int i = 0; i < 8; i++) t[kr][d0 + i] = v[i];
    }
    __syncthreads();
    #pragma unroll
    for (int it = 0; it < 2; it++) {
        int flat = it * 256 + tid;
        int d  = flat >> 3;             // 0..63
        int kc = (flat & 7) * 8;
        bf16x8 o;
        #pragma unroll
        for (int i = 0; i < 8; i++) o[i] = t[kc + i][d];
        *(bf16x8*)&vt[((size_t)bh * 64 + d) * SEQ + k0 + kc] = o;
    }
}

// ---------------------------------------------------------------------------
// bf16 MFMA GEMM (B^T form): C[M,N] = A[M,K] @ Bt[N,K]^T + bias[N]
// 128x128 block tile, 4 waves (2x2), each wave 64x64 via 4x4 frags of
// mfma_f32_16x16x32_bf16. BK=32. global_load_lds width-16 staging (m97).
// ---------------------------------------------------------------------------
template<bool OUT_BF16>
__global__ __launch_bounds__(256) void gemm_bt_mfma(
    const __bf16* __restrict__ A,   // [M,K]
    const __bf16* __restrict__ Bt,  // [N,K]
    const float* __restrict__ bias, // [N]
    void* __restrict__ Cv,          // [M,N]
    int M, int N, int K)
{
    __shared__ __align__(16) __bf16 As[128 * 32];
    __shared__ __align__(16) __bf16 Bs[128 * 32];

    const int tid  = threadIdx.x;
    const int lane = tid & 63;
    const int wave = tid >> 6;
    const int wm = (wave >> 1) * 64;
    const int wn = (wave & 1) * 64;
    const int m0 = blockIdx.y * 128;
    const int n0 = blockIdx.x * 128;
    const int lm = lane & 15;
    const int kq = lane >> 4;

    f32x4 acc[4][4] = {};

    for (int k0 = 0; k0 < K; k0 += 32) {
        __syncthreads();
        #pragma unroll
        for (int r = 0; r < 2; r++) {
            int flat = r * 256 + tid;
            int row  = flat >> 2;
            int off  = (flat & 3) * 16;
            const char* ga = (const char*)(A + (size_t)(m0 + row) * K + k0) + off;
            char* la = (char*)As + flat * 16;
            __builtin_amdgcn_global_load_lds(
                (const __attribute__((address_space(1))) void*)ga,
                (__attribute__((address_space(3))) void*)la, 16, 0, 0);
            const char* gb = (const char*)(Bt + (size_t)(n0 + row) * K + k0) + off;
            char* lb = (char*)Bs + flat * 16;
            __builtin_amdgcn_global_load_lds(
                (const __attribute__((address_space(1))) void*)gb,
                (__attribute__((address_space(3))) void*)lb, 16, 0, 0);
        }
        __syncthreads();

        bf16x8 af[4], bf[4];
        #pragma unroll
        for (int t = 0; t < 4; t++) {
            af[t] = *(const bf16x8*)&As[(wm + t * 16 + lm) * 32 + kq * 8];
            bf[t] = *(const bf16x8*)&Bs[(wn + t * 16 + lm) * 32 + kq * 8];
        }
        #pragma unroll
        for (int i = 0; i < 4; i++)
            #pragma unroll
            for (int j = 0; j < 4; j++)
                acc[i][j] = __builtin_amdgcn_mfma_f32_16x16x32_bf16(
                    af[i], bf[j], acc[i][j], 0, 0, 0);
    }

    const int r0 = kq * 4;
    #pragma unroll
    for (int i = 0; i < 4; i++) {
        #pragma unroll
        for (int j = 0; j < 4; j++) {
            int col = n0 + wn + j * 16 + lm;
            float bv = bias[col];
            #pragma unroll
            for (int r = 0; r < 4; r++) {
                int row = m0 + wm + i * 16 + r0 + r;
                float val = acc[i][j][r] + bv;
                if (OUT_BF16) ((__bf16*)Cv)[(size_t)row * N + col] = (__bf16)val;
                else          ((float*)Cv)[(size_t)row * N + col] = val;
            }
        }
    }
}

// ---------------------------------------------------------------------------
// MFMA flash attention (causal), bf16 in/out, fp32 accum. BARRIER-FREE k-loop:
// Q A-frags, K B-frags, and V^T B-frags (from pre-transposed vt) are all
// contiguous 16B/lane direct global loads. Only LDS use is the wave-private
// P C-layout -> A-layout round trip (intra-wave ordering via lgkmcnt; LDS
// pipe is in-order per wave, so no barriers needed).
// Block = 4 waves x 16 q-rows = 64 q-rows per block.
// ---------------------------------------------------------------------------
__global__ __launch_bounds__(256) void attn_flash_mfma(
    const __bf16* __restrict__ qkv, const __bf16* __restrict__ vt,
    __bf16* __restrict__ attn)
{
    __shared__ __align__(16) __bf16 Pbuf[4][1024];      // per-wave, lane-ordered

    const int tid  = threadIdx.x;
    const int wave = tid >> 6;
    const int lane = tid & 63;
    const int quad = lane >> 4;
    const int c    = lane & 15;

    const int bh = blockIdx.x;
    const int b  = bh >> 4;
    const int h  = bh & 15;
    const int qt = (int)(gridDim.y - 1) - blockIdx.y;   // heavy tiles first
    const int q0 = qt * 64;

    const size_t base = (size_t)b * SEQ * QKV3;
    const int hoff = h * HDIM;
    const int myqrow = quad * 4;
    const __bf16* vbase = vt + (size_t)bh * 64 * SEQ;

    // Q A-fragments (2 k-steps over d), direct from global
    bf16x8 aq0, aq1;
    {
        const __bf16* qrow = qkv + base + (size_t)(q0 + wave * 16 + c) * QKV3 + hoff + quad * 8;
        aq0 = *(const bf16x8*)(qrow);
        aq1 = *(const bf16x8*)(qrow + 32);
    }

    f32x4 acc[4] = {};     // O accumulator (d-frags), unnormalized
    float lpart[4] = {};   // per-row partial softmax denominators

    __bf16* pb = &Pbuf[wave][0];

    for (int k0 = 0; k0 <= q0; k0 += 64) {
        // S = Q K^T : 4 col-frags, K B-frags direct from global
        f32x4 S[4];
        #pragma unroll
        for (int jj = 0; jj < 4; jj++) {
            const __bf16* krow = qkv + base + (size_t)(k0 + jj * 16 + c) * QKV3 + EMBD + hoff + quad * 8;
            bf16x8 bk0 = *(const bf16x8*)(krow);
            bf16x8 bk1 = *(const bf16x8*)(krow + 32);
            f32x4 s = {};
            s = __builtin_amdgcn_mfma_f32_16x16x32_bf16(aq0, bk0, s, 0, 0, 0);
            s = __builtin_amdgcn_mfma_f32_16x16x32_bf16(aq1, bk1, s, 0, 0, 0);
            S[jj] = s;
        }

        // Unnormalized softmax: p = exp(s/8); causal mask on diagonal tile
        const bool diag = (k0 == q0);
        #pragma unroll
        for (int jj = 0; jj < 4; jj++) {
            #pragma unroll
            for (int r = 0; r < 4; r++) {
                float p;
                if (diag && (jj * 16 + c > wave * 16 + myqrow + r)) {
                    p = 0.f;
                } else {
                    p = __expf(fminf(S[jj][r] * 0.125f, 60.f));
                }
                S[jj][r] = p;
                lpart[r] += p;
            }
        }

        // P -> wave-private LDS in A-operand lane order
        #pragma unroll
        for (int jj = 0; jj < 4; jj++) {
            int col = jj * 16 + c;
            int ab  = (col >> 5) * 1024 + ((col >> 3) & 3) * 256 + (col & 7) * 2;
            #pragma unroll
            for (int r = 0; r < 4; r++) {
                *(__bf16*)((char*)pb + ab + (myqrow + r) * 16) = (__bf16)S[jj][r];
            }
        }
        bf16x8 ap0 = *(const bf16x8*)((char*)pb + lane * 16);
        bf16x8 ap1 = *(const bf16x8*)((char*)pb + 1024 + lane * 16);

        // O += P V  (V^T B-frags direct from vt global, contiguous 16B/lane)
        #pragma unroll
        for (int dd = 0; dd < 4; dd++) {
            const __bf16* vr = vbase + (size_t)(dd * 16 + c) * SEQ + k0 + quad * 8;
            bf16x8 bv0 = *(const bf16x8*)(vr);
            bf16x8 bv1 = *(const bf16x8*)(vr + 32);
            acc[dd] = __builtin_amdgcn_mfma_f32_16x16x32_bf16(ap0, bv0, acc[dd], 0, 0, 0);
            acc[dd] = __builtin_amdgcn_mfma_f32_16x16x32_bf16(ap1, bv1, acc[dd], 0, 0, 0);
        }
    }

    // Reduce l across the 16-lane column group
    float inv[4];
    #pragma unroll
    for (int r = 0; r < 4; r++) {
        float v = lpart[r];
        v += __shfl_xor(v, 1);
        v += __shfl_xor(v, 2);
        v += __shfl_xor(v, 4);
        v += __shfl_xor(v, 8);
        inv[r] = 1.f / v;
    }
    // Write O (C layout: row = quad*4+r, col = dd*16+c)
    #pragma unroll
    for (int dd = 0; dd < 4; dd++) {
        #pragma unroll
        for (int r = 0; r < 4; r++) {
            int qrow = q0 + wave * 16 + myqrow + r;
            attn[((size_t)b * SEQ + qrow) * EMBD + hoff + dd * 16 + c] =
                (__bf16)(acc[dd][r] * inv[r]);
        }
    }
}

// ---------------------------------------------------------------------------
extern "C" void kernel_launch(void* const* d_in, const int* in_sizes, int n_in,
                              void* d_out, int out_size, void* d_ws, size_t ws_size,
                              hipStream_t stream)
{
    const float* x     = (const float*)d_in[0];  // [2,2048,1024]
    const float* W_qkv = (const float*)d_in[1];  // [1024,3072]
    const float* b_qkv = (const float*)d_in[2];  // [3072]
    const float* W_out = (const float*)d_in[3];  // [1024,1024]
    const float* b_out = (const float*)d_in[4];  // [1024]
    float* out = (float*)d_out;                  // [2,2048,1024] fp32

    const int M = BATCH * SEQ;   // 4096

    __bf16* xbf    = (__bf16*)d_ws;                          // [4096,1024]  8 MB
    __bf16* Wqkv_t = xbf    + (size_t)M * EMBD;              // [3072,1024]  6 MB
    __bf16* Wout_t = Wqkv_t + (size_t)QKV3 * EMBD;           // [1024,1024]  2 MB
    __bf16* qkv    = Wout_t + (size_t)EMBD * EMBD;           // [4096,3072] 24 MB
    __bf16* attn   = qkv    + (size_t)M * QKV3;              // [4096,1024]  8 MB
    __bf16* vtbuf  = attn   + (size_t)M * EMBD;              // [32,64,2048]  8 MB

    // 0) Casts
    cast_f32_bf16<<<(M * EMBD) / (256 * 8), 256, 0, stream>>>(x, xbf);
    {
        dim3 g(QKV3 / 64, EMBD / 64);
        transpose_cast_bf16<<<g, 256, 0, stream>>>(W_qkv, Wqkv_t, EMBD, QKV3);
    }
    {
        dim3 g(EMBD / 64, EMBD / 64);
        transpose_cast_bf16<<<g, 256, 0, stream>>>(W_out, Wout_t, EMBD, EMBD);
    }
    // 1) QKV projection (bf16 out)
    {
        dim3 grid(QKV3 / 128, M / 128);
        gemm_bt_mfma<true><<<grid, 256, 0, stream>>>(xbf, Wqkv_t, b_qkv, qkv, M, QKV3, EMBD);
    }
    // 1b) Pre-transpose V to [bh][d][k]
    {
        dim3 grid(SEQ / 64, BATCH * NHEAD);
        transpose_v_bf16<<<grid, 256, 0, stream>>>(qkv, vtbuf);
    }
    // 2) Barrier-free MFMA flash causal attention
    {
        dim3 grid(BATCH * NHEAD, SEQ / 64);
        attn_flash_mfma<<<grid, 256, 0, stream>>>(qkv, vtbuf, attn);
    }
    // 3) Output projection (fp32 out)
    {
        dim3 grid(EMBD / 128, M / 128);
        gemm_bt_mfma<false><<<grid, 256, 0, stream>>>(attn, Wout_t, b_out, out, M, EMBD, EMBD);
    }
}

// Round 6
// 238.285 us; speedup vs baseline: 1.1931x; 1.1931x over previous
//
#include <hip/hip_runtime.h>
#include <hip/hip_bf16.h>

// Problem constants
#define BATCH 2
#define SEQ   2048
#define EMBD  1024
#define NHEAD 16
#define HDIM  64
#define QKV3  (3 * EMBD)   // 3072

typedef __attribute__((ext_vector_type(8))) __bf16 bf16x8;
typedef __attribute__((ext_vector_type(4))) __bf16 bf16x4;
typedef __attribute__((ext_vector_type(4))) float f32x4;

// ---------------------------------------------------------------------------
// fp32 -> bf16 elementwise cast (8 elems/thread)
// ---------------------------------------------------------------------------
__global__ __launch_bounds__(256) void cast_f32_bf16(
    const float* __restrict__ in, __bf16* __restrict__ out)
{
    int i = (blockIdx.x * 256 + threadIdx.x) * 8;
    float4 a = *(const float4*)&in[i];
    float4 b = *(const float4*)&in[i + 4];
    bf16x8 o;
    o[0] = (__bf16)a.x; o[1] = (__bf16)a.y; o[2] = (__bf16)a.z; o[3] = (__bf16)a.w;
    o[4] = (__bf16)b.x; o[5] = (__bf16)b.y; o[6] = (__bf16)b.z; o[7] = (__bf16)b.w;
    *(bf16x8*)&out[i] = o;
}

// ---------------------------------------------------------------------------
// fp32 [K,N] -> bf16 [N,K] transpose+cast, 64x64 LDS tile, 256 threads
// ---------------------------------------------------------------------------
__global__ __launch_bounds__(256) void transpose_cast_bf16(
    const float* __restrict__ in, __bf16* __restrict__ out, int K, int N)
{
    __shared__ float t[64][65];
    const int k0 = blockIdx.y * 64, n0 = blockIdx.x * 64;
    const int tid = threadIdx.x;
    #pragma unroll
    for (int p = 0; p < 4; p++) {
        int kr = p * 16 + (tid >> 4);
        int c4 = (tid & 15) * 4;
        float4 v = *(const float4*)&in[(size_t)(k0 + kr) * N + n0 + c4];
        t[kr][c4] = v.x; t[kr][c4 + 1] = v.y; t[kr][c4 + 2] = v.z; t[kr][c4 + 3] = v.w;
    }
    __syncthreads();
    #pragma unroll
    for (int p = 0; p < 4; p++) {
        int nr = p * 16 + (tid >> 4);
        int k4 = (tid & 15) * 4;
        bf16x4 o;
        o[0] = (__bf16)t[k4 + 0][nr];
        o[1] = (__bf16)t[k4 + 1][nr];
        o[2] = (__bf16)t[k4 + 2][nr];
        o[3] = (__bf16)t[k4 + 3][nr];
        *(bf16x4*)&out[(size_t)(n0 + nr) * K + k0 + k4] = o;
    }
}

// ---------------------------------------------------------------------------
// bf16 V-transpose: qkv V region [k][d] per (b,h) -> vt[bh][d][k]
// ---------------------------------------------------------------------------
__global__ __launch_bounds__(256) void transpose_v_bf16(
    const __bf16* __restrict__ qkv, __bf16* __restrict__ vt)
{
    __shared__ __bf16 t[64][72];
    const int k0 = blockIdx.x * 64;
    const int bh = blockIdx.y;
    const int b = bh >> 4, h = bh & 15;
    const size_t base = (size_t)b * SEQ * QKV3 + 2 * EMBD + h * HDIM;
    const int tid = threadIdx.x;
    #pragma unroll
    for (int it = 0; it < 2; it++) {
        int flat = it * 256 + tid;      // 0..511
        int kr = flat >> 3;             // 0..63
        int d0 = (flat & 7) * 8;
        bf16x8 v = *(const bf16x8*)&qkv[base + (size_t)(k0 + kr) * QKV3 + d0];
        #pragma unroll
        for (int i = 0; i < 8; i++) t[kr][d0 + i] = v[i];
    }
    __syncthreads();
    #pragma unroll
    for (int it = 0; it < 2; it++) {
        int flat = it * 256 + tid;
        int d  = flat >> 3;             // 0..63
        int kc = (flat & 7) * 8;
        bf16x8 o;
        #pragma unroll
        for (int i = 0; i < 8; i++) o[i] = t[kc + i][d];
        *(bf16x8*)&vt[((size_t)bh * 64 + d) * SEQ + k0 + kc] = o;
    }
}

// ---------------------------------------------------------------------------
// bf16 MFMA GEMM (B^T form): C[M,N] = A[M,K] @ Bt[N,K]^T + bias[N]
// 128x128 block tile, 4 waves (2x2), mfma_f32_16x16x32_bf16, BK=32,
// global_load_lds width-16 staging (m97 ladder).
// ---------------------------------------------------------------------------
template<bool OUT_BF16>
__global__ __launch_bounds__(256) void gemm_bt_mfma(
    const __bf16* __restrict__ A,   // [M,K]
    const __bf16* __restrict__ Bt,  // [N,K]
    const float* __restrict__ bias, // [N]
    void* __restrict__ Cv,          // [M,N]
    int M, int N, int K)
{
    __shared__ __align__(16) __bf16 As[128 * 32];
    __shared__ __align__(16) __bf16 Bs[128 * 32];

    const int tid  = threadIdx.x;
    const int lane = tid & 63;
    const int wave = tid >> 6;
    const int wm = (wave >> 1) * 64;
    const int wn = (wave & 1) * 64;
    const int m0 = blockIdx.y * 128;
    const int n0 = blockIdx.x * 128;
    const int lm = lane & 15;
    const int kq = lane >> 4;

    f32x4 acc[4][4] = {};

    for (int k0 = 0; k0 < K; k0 += 32) {
        __syncthreads();
        #pragma unroll
        for (int r = 0; r < 2; r++) {
            int flat = r * 256 + tid;
            int row  = flat >> 2;
            int off  = (flat & 3) * 16;
            const char* ga = (const char*)(A + (size_t)(m0 + row) * K + k0) + off;
            char* la = (char*)As + flat * 16;
            __builtin_amdgcn_global_load_lds(
                (const __attribute__((address_space(1))) void*)ga,
                (__attribute__((address_space(3))) void*)la, 16, 0, 0);
            const char* gb = (const char*)(Bt + (size_t)(n0 + row) * K + k0) + off;
            char* lb = (char*)Bs + flat * 16;
            __builtin_amdgcn_global_load_lds(
                (const __attribute__((address_space(1))) void*)gb,
                (__attribute__((address_space(3))) void*)lb, 16, 0, 0);
        }
        __syncthreads();

        bf16x8 af[4], bf[4];
        #pragma unroll
        for (int t = 0; t < 4; t++) {
            af[t] = *(const bf16x8*)&As[(wm + t * 16 + lm) * 32 + kq * 8];
            bf[t] = *(const bf16x8*)&Bs[(wn + t * 16 + lm) * 32 + kq * 8];
        }
        #pragma unroll
        for (int i = 0; i < 4; i++)
            #pragma unroll
            for (int j = 0; j < 4; j++)
                acc[i][j] = __builtin_amdgcn_mfma_f32_16x16x32_bf16(
                    af[i], bf[j], acc[i][j], 0, 0, 0);
    }

    const int r0 = kq * 4;
    #pragma unroll
    for (int i = 0; i < 4; i++) {
        #pragma unroll
        for (int j = 0; j < 4; j++) {
            int col = n0 + wn + j * 16 + lm;
            float bv = bias[col];
            #pragma unroll
            for (int r = 0; r < 4; r++) {
                int row = m0 + wm + i * 16 + r0 + r;
                float val = acc[i][j][r] + bv;
                if (OUT_BF16) ((__bf16*)Cv)[(size_t)row * N + col] = (__bf16)val;
                else          ((float*)Cv)[(size_t)row * N + col] = val;
            }
        }
    }
}

// ---------------------------------------------------------------------------
// MFMA flash attention (causal), bf16 in/out, fp32 accum.
// Block = 256 threads = 4 waves; block owns 128 q-rows, wave owns 32 (2 frags).
// V^T staged cooperatively from pre-transposed vt into DOUBLE-BUFFERED LDS
// (one __syncthreads per k-tile; next tile's global loads in flight during
// compute). Q/K fragments are direct global loads (contiguous 16B/lane).
// P does the C->A layout round trip through wave-private LDS.
// Unnormalized softmax (p = exp(s/8), clamp 60), divide by row-sum at end.
// ---------------------------------------------------------------------------
__global__ __launch_bounds__(256, 3) void attn_flash_mfma(
    const __bf16* __restrict__ qkv, const __bf16* __restrict__ vt,
    __bf16* __restrict__ attn)
{
    __shared__ __align__(16) __bf16 Vt[2][64 * 72];     // dbuf, stride 72 elems
    __shared__ __align__(16) __bf16 Pbuf[4][2][1024];   // [wave][qf], lane-ordered

    const int tid  = threadIdx.x;
    const int wave = tid >> 6;
    const int lane = tid & 63;
    const int quad = lane >> 4;
    const int c    = lane & 15;

    const int bh = blockIdx.x;
    const int b  = bh >> 4;
    const int h  = bh & 15;
    const int qt = (int)(gridDim.y - 1) - blockIdx.y;   // heavy tiles first
    const int q0 = qt * 128;

    const size_t base = (size_t)b * SEQ * QKV3;
    const int hoff = h * HDIM;
    const int myqrow = quad * 4;
    const __bf16* vbase = vt + (size_t)bh * 64 * SEQ;

    // V staging assignment: thread -> row d, two 16B chunks
    const int vd = tid >> 2;            // 0..63
    const int vc = (tid & 3) * 2;       // chunk pair 0,2,4,6
    const __bf16* vgsrc = vbase + (size_t)vd * SEQ + vc * 8;
    __bf16* vldst = (__bf16*)Vt + vd * 72 + vc * 8;

    // Q A-fragments: 2 q-frags x 2 k-steps, direct from global
    bf16x8 aq[2][2];
    #pragma unroll
    for (int qf = 0; qf < 2; qf++) {
        const __bf16* qrow = qkv + base +
            (size_t)(q0 + wave * 32 + qf * 16 + c) * QKV3 + hoff + quad * 8;
        aq[qf][0] = *(const bf16x8*)(qrow);
        aq[qf][1] = *(const bf16x8*)(qrow + 32);
    }

    f32x4 acc[2][4] = {};      // O accumulators per q-frag
    float lpart[2][4] = {};    // per-row partial softmax denominators

    const int wave_qmax = q0 + wave * 32 + 31;
    const int ntiles = q0 / 64 + 2;     // covers k up to q0+127

    // Preload V regs for tile 0
    bf16x8 vr0 = *(const bf16x8*)(vgsrc);
    bf16x8 vr1 = *(const bf16x8*)(vgsrc + 8);

    for (int t = 0; t < ntiles; t++) {
        const int k0 = t * 64;
        const int buf = t & 1;

        // Commit prefetched V regs to LDS buffer, then barrier
        {
            __bf16* dst = vldst + buf * (64 * 72);
            *(bf16x8*)(dst)     = vr0;
            *(bf16x8*)(dst + 8) = vr1;
        }
        __syncthreads();

        // Prefetch next tile's V into regs (in flight during compute)
        if (t + 1 < ntiles) {
            const __bf16* src = vgsrc + (t + 1) * 64;
            vr0 = *(const bf16x8*)(src);
            vr1 = *(const bf16x8*)(src + 8);
        }

        // Wave-uniform skip: this wave's rows all below k0 -> tile fully masked
        if (k0 > wave_qmax) continue;

        // S = Q K^T : K B-frags shared across both q-frags
        f32x4 S[2][4];
        #pragma unroll
        for (int jj = 0; jj < 4; jj++) {
            const __bf16* krow = qkv + base +
                (size_t)(k0 + jj * 16 + c) * QKV3 + EMBD + hoff + quad * 8;
            bf16x8 bk0 = *(const bf16x8*)(krow);
            bf16x8 bk1 = *(const bf16x8*)(krow + 32);
            #pragma unroll
            for (int qf = 0; qf < 2; qf++) {
                f32x4 s = {};
                s = __builtin_amdgcn_mfma_f32_16x16x32_bf16(aq[qf][0], bk0, s, 0, 0, 0);
                s = __builtin_amdgcn_mfma_f32_16x16x32_bf16(aq[qf][1], bk1, s, 0, 0, 0);
                S[qf][jj] = s;
            }
        }

        // Softmax (unnormalized) + causal mask near diagonal; write P to LDS
        #pragma unroll
        for (int qf = 0; qf < 2; qf++) {
            const int qfbase = q0 + wave * 32 + qf * 16;
            const bool need_mask = (k0 + 63 > qfbase);
            __bf16* pb = &Pbuf[wave][qf][0];
            #pragma unroll
            for (int jj = 0; jj < 4; jj++) {
                int col = jj * 16 + c;
                int ab  = (col >> 5) * 1024 + ((col >> 3) & 3) * 256 + (col & 7) * 2;
                #pragma unroll
                for (int r = 0; r < 4; r++) {
                    float p;
                    if (need_mask && (k0 + col > qfbase + myqrow + r)) {
                        p = 0.f;
                    } else {
                        p = __expf(fminf(S[qf][jj][r] * 0.125f, 60.f));
                    }
                    lpart[qf][r] += p;
                    *(__bf16*)((char*)pb + ab + (myqrow + r) * 16) = (__bf16)p;
                }
            }
        }

        // Read P A-frags back (intra-wave LDS ordering via lgkmcnt)
        bf16x8 ap[2][2];
        #pragma unroll
        for (int qf = 0; qf < 2; qf++) {
            const char* pb = (const char*)&Pbuf[wave][qf][0];
            ap[qf][0] = *(const bf16x8*)(pb + lane * 16);
            ap[qf][1] = *(const bf16x8*)(pb + 1024 + lane * 16);
        }

        // O += P V : V B-frags from LDS, shared across q-frags
        const __bf16* vbuf = (const __bf16*)Vt + buf * (64 * 72);
        #pragma unroll
        for (int dd = 0; dd < 4; dd++) {
            const __bf16* vr = vbuf + (dd * 16 + c) * 72 + quad * 8;
            bf16x8 bv0 = *(const bf16x8*)(vr);
            bf16x8 bv1 = *(const bf16x8*)(vr + 32);
            #pragma unroll
            for (int qf = 0; qf < 2; qf++) {
                acc[qf][dd] = __builtin_amdgcn_mfma_f32_16x16x32_bf16(ap[qf][0], bv0, acc[qf][dd], 0, 0, 0);
                acc[qf][dd] = __builtin_amdgcn_mfma_f32_16x16x32_bf16(ap[qf][1], bv1, acc[qf][dd], 0, 0, 0);
            }
        }
    }

    // Normalize and write out
    #pragma unroll
    for (int qf = 0; qf < 2; qf++) {
        float inv[4];
        #pragma unroll
        for (int r = 0; r < 4; r++) {
            float v = lpart[qf][r];
            v += __shfl_xor(v, 1);
            v += __shfl_xor(v, 2);
            v += __shfl_xor(v, 4);
            v += __shfl_xor(v, 8);
            inv[r] = 1.f / v;
        }
        #pragma unroll
        for (int dd = 0; dd < 4; dd++) {
            #pragma unroll
            for (int r = 0; r < 4; r++) {
                int qrow = q0 + wave * 32 + qf * 16 + myqrow + r;
                attn[((size_t)b * SEQ + qrow) * EMBD + hoff + dd * 16 + c] =
                    (__bf16)(acc[qf][dd][r] * inv[r]);
            }
        }
    }
}

// ---------------------------------------------------------------------------
extern "C" void kernel_launch(void* const* d_in, const int* in_sizes, int n_in,
                              void* d_out, int out_size, void* d_ws, size_t ws_size,
                              hipStream_t stream)
{
    const float* x     = (const float*)d_in[0];  // [2,2048,1024]
    const float* W_qkv = (const float*)d_in[1];  // [1024,3072]
    const float* b_qkv = (const float*)d_in[2];  // [3072]
    const float* W_out = (const float*)d_in[3];  // [1024,1024]
    const float* b_out = (const float*)d_in[4];  // [1024]
    float* out = (float*)d_out;                  // [2,2048,1024] fp32

    const int M = BATCH * SEQ;   // 4096

    __bf16* xbf    = (__bf16*)d_ws;                          // [4096,1024]  8 MB
    __bf16* Wqkv_t = xbf    + (size_t)M * EMBD;              // [3072,1024]  6 MB
    __bf16* Wout_t = Wqkv_t + (size_t)QKV3 * EMBD;           // [1024,1024]  2 MB
    __bf16* qkv    = Wout_t + (size_t)EMBD * EMBD;           // [4096,3072] 24 MB
    __bf16* attn   = qkv    + (size_t)M * QKV3;              // [4096,1024]  8 MB
    __bf16* vtbuf  = attn   + (size_t)M * EMBD;              // [32,64,2048]  8 MB

    // 0) Casts
    cast_f32_bf16<<<(M * EMBD) / (256 * 8), 256, 0, stream>>>(x, xbf);
    {
        dim3 g(QKV3 / 64, EMBD / 64);
        transpose_cast_bf16<<<g, 256, 0, stream>>>(W_qkv, Wqkv_t, EMBD, QKV3);
    }
    {
        dim3 g(EMBD / 64, EMBD / 64);
        transpose_cast_bf16<<<g, 256, 0, stream>>>(W_out, Wout_t, EMBD, EMBD);
    }
    // 1) QKV projection (bf16 out)
    {
        dim3 grid(QKV3 / 128, M / 128);
        gemm_bt_mfma<true><<<grid, 256, 0, stream>>>(xbf, Wqkv_t, b_qkv, qkv, M, QKV3, EMBD);
    }
    // 1b) Pre-transpose V to [bh][d][k]
    {
        dim3 grid(SEQ / 64, BATCH * NHEAD);
        transpose_v_bf16<<<grid, 256, 0, stream>>>(qkv, vtbuf);
    }
    // 2) MFMA flash causal attention (dbuf LDS V, 128 q/block)
    {
        dim3 grid(BATCH * NHEAD, SEQ / 128);
        attn_flash_mfma<<<grid, 256, 0, stream>>>(qkv, vtbuf, attn);
    }
    // 3) Output projection (fp32 out)
    {
        dim3 grid(EMBD / 128, M / 128);
        gemm_bt_mfma<false><<<grid, 256, 0, stream>>>(attn, Wout_t, b_out, out, M, EMBD, EMBD);
    }
}

// Round 7
// 219.599 us; speedup vs baseline: 1.2946x; 1.0851x over previous
//
#include <hip/hip_runtime.h>
#include <hip/hip_bf16.h>

// Problem constants
#define BATCH 2
#define SEQ   2048
#define EMBD  1024
#define NHEAD 16
#define HDIM  64
#define QKV3  (3 * EMBD)   // 3072

typedef __attribute__((ext_vector_type(8))) __bf16 bf16x8;
typedef __attribute__((ext_vector_type(4))) __bf16 bf16x4;
typedef __attribute__((ext_vector_type(4))) float f32x4;

// ---------------------------------------------------------------------------
// fp32 -> bf16 elementwise cast (8 elems/thread)
// ---------------------------------------------------------------------------
__global__ __launch_bounds__(256) void cast_f32_bf16(
    const float* __restrict__ in, __bf16* __restrict__ out)
{
    int i = (blockIdx.x * 256 + threadIdx.x) * 8;
    float4 a = *(const float4*)&in[i];
    float4 b = *(const float4*)&in[i + 4];
    bf16x8 o;
    o[0] = (__bf16)a.x; o[1] = (__bf16)a.y; o[2] = (__bf16)a.z; o[3] = (__bf16)a.w;
    o[4] = (__bf16)b.x; o[5] = (__bf16)b.y; o[6] = (__bf16)b.z; o[7] = (__bf16)b.w;
    *(bf16x8*)&out[i] = o;
}

// ---------------------------------------------------------------------------
// fp32 [K,N] -> bf16 [N,K] transpose+cast, 64x64 LDS tile, 256 threads
// ---------------------------------------------------------------------------
__global__ __launch_bounds__(256) void transpose_cast_bf16(
    const float* __restrict__ in, __bf16* __restrict__ out, int K, int N)
{
    __shared__ float t[64][65];
    const int k0 = blockIdx.y * 64, n0 = blockIdx.x * 64;
    const int tid = threadIdx.x;
    #pragma unroll
    for (int p = 0; p < 4; p++) {
        int kr = p * 16 + (tid >> 4);
        int c4 = (tid & 15) * 4;
        float4 v = *(const float4*)&in[(size_t)(k0 + kr) * N + n0 + c4];
        t[kr][c4] = v.x; t[kr][c4 + 1] = v.y; t[kr][c4 + 2] = v.z; t[kr][c4 + 3] = v.w;
    }
    __syncthreads();
    #pragma unroll
    for (int p = 0; p < 4; p++) {
        int nr = p * 16 + (tid >> 4);
        int k4 = (tid & 15) * 4;
        bf16x4 o;
        o[0] = (__bf16)t[k4 + 0][nr];
        o[1] = (__bf16)t[k4 + 1][nr];
        o[2] = (__bf16)t[k4 + 2][nr];
        o[3] = (__bf16)t[k4 + 3][nr];
        *(bf16x4*)&out[(size_t)(n0 + nr) * K + k0 + k4] = o;
    }
}

// ---------------------------------------------------------------------------
// bf16 V-transpose: qkv V region [k][d] per (b,h) -> vt[bh][d][k]
// ---------------------------------------------------------------------------
__global__ __launch_bounds__(256) void transpose_v_bf16(
    const __bf16* __restrict__ qkv, __bf16* __restrict__ vt)
{
    __shared__ __bf16 t[64][72];
    const int k0 = blockIdx.x * 64;
    const int bh = blockIdx.y;
    const int b = bh >> 4, h = bh & 15;
    const size_t base = (size_t)b * SEQ * QKV3 + 2 * EMBD + h * HDIM;
    const int tid = threadIdx.x;
    #pragma unroll
    for (int it = 0; it < 2; it++) {
        int flat = it * 256 + tid;      // 0..511
        int kr = flat >> 3;             // 0..63
        int d0 = (flat & 7) * 8;
        bf16x8 v = *(const bf16x8*)&qkv[base + (size_t)(k0 + kr) * QKV3 + d0];
        #pragma unroll
        for (int i = 0; i < 8; i++) t[kr][d0 + i] = v[i];
    }
    __syncthreads();
    #pragma unroll
    for (int it = 0; it < 2; it++) {
        int flat = it * 256 + tid;
        int d  = flat >> 3;             // 0..63
        int kc = (flat & 7) * 8;
        bf16x8 o;
        #pragma unroll
        for (int i = 0; i < 8; i++) o[i] = t[kc + i][d];
        *(bf16x8*)&vt[((size_t)bh * 64 + d) * SEQ + k0 + kc] = o;
    }
}

// ---------------------------------------------------------------------------
// bf16 MFMA GEMM (B^T form): C[M,N] = A[M,K] @ Bt[N,K]^T + bias[N]
// 128x128 block tile, 4 waves (2x2), mfma_f32_16x16x32_bf16, BK=32,
// global_load_lds width-16 staging. Columns < nscale get *0.125 (folds the
// attention 1/sqrt(d) into the Q region of the QKV projection; exact pow2).
// ---------------------------------------------------------------------------
template<bool OUT_BF16>
__global__ __launch_bounds__(256) void gemm_bt_mfma(
    const __bf16* __restrict__ A,   // [M,K]
    const __bf16* __restrict__ Bt,  // [N,K]
    const float* __restrict__ bias, // [N]
    void* __restrict__ Cv,          // [M,N]
    int M, int N, int K, int nscale)
{
    __shared__ __align__(16) __bf16 As[128 * 32];
    __shared__ __align__(16) __bf16 Bs[128 * 32];

    const int tid  = threadIdx.x;
    const int lane = tid & 63;
    const int wave = tid >> 6;
    const int wm = (wave >> 1) * 64;
    const int wn = (wave & 1) * 64;
    const int m0 = blockIdx.y * 128;
    const int n0 = blockIdx.x * 128;
    const int lm = lane & 15;
    const int kq = lane >> 4;

    f32x4 acc[4][4] = {};

    for (int k0 = 0; k0 < K; k0 += 32) {
        __syncthreads();
        #pragma unroll
        for (int r = 0; r < 2; r++) {
            int flat = r * 256 + tid;
            int row  = flat >> 2;
            int off  = (flat & 3) * 16;
            const char* ga = (const char*)(A + (size_t)(m0 + row) * K + k0) + off;
            char* la = (char*)As + flat * 16;
            __builtin_amdgcn_global_load_lds(
                (const __attribute__((address_space(1))) void*)ga,
                (__attribute__((address_space(3))) void*)la, 16, 0, 0);
            const char* gb = (const char*)(Bt + (size_t)(n0 + row) * K + k0) + off;
            char* lb = (char*)Bs + flat * 16;
            __builtin_amdgcn_global_load_lds(
                (const __attribute__((address_space(1))) void*)gb,
                (__attribute__((address_space(3))) void*)lb, 16, 0, 0);
        }
        __syncthreads();

        bf16x8 af[4], bf[4];
        #pragma unroll
        for (int t = 0; t < 4; t++) {
            af[t] = *(const bf16x8*)&As[(wm + t * 16 + lm) * 32 + kq * 8];
            bf[t] = *(const bf16x8*)&Bs[(wn + t * 16 + lm) * 32 + kq * 8];
        }
        #pragma unroll
        for (int i = 0; i < 4; i++)
            #pragma unroll
            for (int j = 0; j < 4; j++)
                acc[i][j] = __builtin_amdgcn_mfma_f32_16x16x32_bf16(
                    af[i], bf[j], acc[i][j], 0, 0, 0);
    }

    const int r0 = kq * 4;
    #pragma unroll
    for (int i = 0; i < 4; i++) {
        #pragma unroll
        for (int j = 0; j < 4; j++) {
            int col = n0 + wn + j * 16 + lm;
            float bv = bias[col];
            float sc = (col < nscale) ? 0.125f : 1.0f;
            #pragma unroll
            for (int r = 0; r < 4; r++) {
                int row = m0 + wm + i * 16 + r0 + r;
                float val = (acc[i][j][r] + bv) * sc;
                if (OUT_BF16) ((__bf16*)Cv)[(size_t)row * N + col] = (__bf16)val;
                else          ((float*)Cv)[(size_t)row * N + col] = val;
            }
        }
    }
}

// ---------------------------------------------------------------------------
// K-parallel MFMA flash attention (causal), bf16 in/out, fp32 accum.
// Block = 256 threads = 4 waves; block owns 32 q-rows (2 frags/wave).
// Wave w processes k-tiles t = w, w+4, ... INDEPENDENTLY (no barriers in the
// k-loop) accumulating private unnormalized (O, l) — additive because the
// softmax has no running max (p = exp(s), s pre-scaled, clamp 60).
// End: 3-barrier LDS tree combine of the 4 waves' partials, then normalize.
// Q/K/V^T fragments all direct global 16B/lane loads; P does the C->A layout
// round trip via wave-private LDS (in-order per-wave LDS pipe, no barrier).
// ---------------------------------------------------------------------------
__global__ __launch_bounds__(256) void attn_kpar_mfma(
    const __bf16* __restrict__ qkv, const __bf16* __restrict__ vt,
    __bf16* __restrict__ attn)
{
    // smem: loop phase = Pbuf[4 waves][2 qf][2048 B] = 16384 B
    //       combine    = Ored[2][32][65] f32 (16640 B) + lred[2][32] (256 B)
    __shared__ __align__(16) char smem[16896];

    const int tid  = threadIdx.x;
    const int wave = tid >> 6;
    const int lane = tid & 63;
    const int quad = lane >> 4;
    const int c    = lane & 15;

    const int bh = blockIdx.x;
    const int b  = bh >> 4;
    const int h  = bh & 15;
    const int qblk = (int)(gridDim.y - 1) - blockIdx.y;   // heavy first
    const int q0 = qblk * 32;

    const size_t base = (size_t)b * SEQ * QKV3;
    const int hoff = h * HDIM;
    const __bf16* vbase = vt + (size_t)bh * 64 * SEQ;

    // Q A-frags (pre-scaled by 0.125 in the QKV GEMM epilogue)
    bf16x8 aq[2][2];
    #pragma unroll
    for (int qf = 0; qf < 2; qf++) {
        const __bf16* qrow = qkv + base +
            (size_t)(q0 + qf * 16 + c) * QKV3 + hoff + quad * 8;
        aq[qf][0] = *(const bf16x8*)(qrow);
        aq[qf][1] = *(const bf16x8*)(qrow + 32);
    }

    f32x4 acc[2][4] = {};
    float lpart[2][4] = {};

    char* pbw = smem + wave * 4096;
    const int ntiles = q0 / 64 + 1;    // k-tiles covering [0, q0+31]

    for (int t = wave; t < ntiles; t += 4) {
        const int k0 = t * 64;
        const bool diag = (t == ntiles - 1);

        // S = Q K^T, exp, write P (per jj, per qf)
        #pragma unroll
        for (int jj = 0; jj < 4; jj++) {
            const __bf16* krow = qkv + base +
                (size_t)(k0 + jj * 16 + c) * QKV3 + EMBD + hoff + quad * 8;
            bf16x8 bk0 = *(const bf16x8*)(krow);
            bf16x8 bk1 = *(const bf16x8*)(krow + 32);
            const int kabs_c = k0 + jj * 16 + c;
            const int col = jj * 16 + c;
            const int ab = (col >> 5) * 1024 + ((col >> 3) & 3) * 256 + (col & 7) * 2;
            #pragma unroll
            for (int qf = 0; qf < 2; qf++) {
                f32x4 s = {};
                s = __builtin_amdgcn_mfma_f32_16x16x32_bf16(aq[qf][0], bk0, s, 0, 0, 0);
                s = __builtin_amdgcn_mfma_f32_16x16x32_bf16(aq[qf][1], bk1, s, 0, 0, 0);
                char* pq = pbw + qf * 2048 + ab;
                const int qabs0 = q0 + qf * 16 + quad * 4;
                #pragma unroll
                for (int r = 0; r < 4; r++) {
                    float p;
                    if (diag && (kabs_c > qabs0 + r)) p = 0.f;
                    else p = __expf(fminf(s[r], 60.f));
                    lpart[qf][r] += p;
                    *(__bf16*)(pq + (quad * 4 + r) * 16) = (__bf16)p;
                }
            }
        }

        // P A-frag readback (wave-private; per-wave LDS pipe is in-order)
        bf16x8 ap[2][2];
        #pragma unroll
        for (int qf = 0; qf < 2; qf++) {
            ap[qf][0] = *(const bf16x8*)(pbw + qf * 2048 + lane * 16);
            ap[qf][1] = *(const bf16x8*)(pbw + qf * 2048 + 1024 + lane * 16);
        }

        // O += P V : V^T B-frags direct from vt
        #pragma unroll
        for (int dd = 0; dd < 4; dd++) {
            const __bf16* vr = vbase + (size_t)(dd * 16 + c) * SEQ + k0 + quad * 8;
            bf16x8 bv0 = *(const bf16x8*)(vr);
            bf16x8 bv1 = *(const bf16x8*)(vr + 32);
            #pragma unroll
            for (int qf = 0; qf < 2; qf++) {
                acc[qf][dd] = __builtin_amdgcn_mfma_f32_16x16x32_bf16(ap[qf][0], bv0, acc[qf][dd], 0, 0, 0);
                acc[qf][dd] = __builtin_amdgcn_mfma_f32_16x16x32_bf16(ap[qf][1], bv1, acc[qf][dd], 0, 0, 0);
            }
        }
    }

    // Full row-sums of l within wave (reduce over the 16 c-lanes)
    #pragma unroll
    for (int qf = 0; qf < 2; qf++)
        #pragma unroll
        for (int r = 0; r < 4; r++) {
            float v = lpart[qf][r];
            v += __shfl_xor(v, 1);
            v += __shfl_xor(v, 2);
            v += __shfl_xor(v, 4);
            v += __shfl_xor(v, 8);
            lpart[qf][r] = v;
        }

    __syncthreads();   // done with Pbuf; reuse smem for the combine

    float* Ored = (float*)smem;                    // [2][32][65]
    float* lred = (float*)(smem + 16640);          // [2][32]

    if (wave < 2) {
        float* R = Ored + wave * (32 * 65);
        #pragma unroll
        for (int qf = 0; qf < 2; qf++)
            #pragma unroll
            for (int dd = 0; dd < 4; dd++)
                #pragma unroll
                for (int r = 0; r < 4; r++)
                    R[(qf * 16 + quad * 4 + r) * 65 + dd * 16 + c] = acc[qf][dd][r];
        if (c == 0) {
            #pragma unroll
            for (int qf = 0; qf < 2; qf++)
                #pragma unroll
                for (int r = 0; r < 4; r++)
                    lred[wave * 32 + qf * 16 + quad * 4 + r] = lpart[qf][r];
        }
    }
    __syncthreads();
    if (wave >= 2) {
        float* R = Ored + (wave - 2) * (32 * 65);
        #pragma unroll
        for (int qf = 0; qf < 2; qf++)
            #pragma unroll
            for (int dd = 0; dd < 4; dd++)
                #pragma unroll
                for (int r = 0; r < 4; r++)
                    R[(qf * 16 + quad * 4 + r) * 65 + dd * 16 + c] += acc[qf][dd][r];
        if (c == 0) {
            #pragma unroll
            for (int qf = 0; qf < 2; qf++)
                #pragma unroll
                for (int r = 0; r < 4; r++)
                    lred[(wave - 2) * 32 + qf * 16 + quad * 4 + r] += lpart[qf][r];
        }
    }
    __syncthreads();

    // Final: 256 threads, each one 8-col chunk of one row
    {
        const int row = tid >> 3;          // 0..31
        const int cg  = tid & 7;           // 8-col group
        const float l = lred[row] + lred[32 + row];
        const float inv = 1.f / l;
        const float* R0 = Ored + row * 65 + cg * 8;
        const float* R1 = R0 + 32 * 65;
        bf16x8 o;
        #pragma unroll
        for (int i = 0; i < 8; i++) o[i] = (__bf16)((R0[i] + R1[i]) * inv);
        *(bf16x8*)&attn[((size_t)b * SEQ + q0 + row) * EMBD + hoff + cg * 8] = o;
    }
}

// ---------------------------------------------------------------------------
extern "C" void kernel_launch(void* const* d_in, const int* in_sizes, int n_in,
                              void* d_out, int out_size, void* d_ws, size_t ws_size,
                              hipStream_t stream)
{
    const float* x     = (const float*)d_in[0];  // [2,2048,1024]
    const float* W_qkv = (const float*)d_in[1];  // [1024,3072]
    const float* b_qkv = (const float*)d_in[2];  // [3072]
    const float* W_out = (const float*)d_in[3];  // [1024,1024]
    const float* b_out = (const float*)d_in[4];  // [1024]
    float* out = (float*)d_out;                  // [2,2048,1024] fp32

    const int M = BATCH * SEQ;   // 4096

    __bf16* xbf    = (__bf16*)d_ws;                          // [4096,1024]  8 MB
    __bf16* Wqkv_t = xbf    + (size_t)M * EMBD;              // [3072,1024]  6 MB
    __bf16* Wout_t = Wqkv_t + (size_t)QKV3 * EMBD;           // [1024,1024]  2 MB
    __bf16* qkv    = Wout_t + (size_t)EMBD * EMBD;           // [4096,3072] 24 MB
    __bf16* attn   = qkv    + (size_t)M * QKV3;              // [4096,1024]  8 MB
    __bf16* vtbuf  = attn   + (size_t)M * EMBD;              // [32,64,2048]  8 MB

    // 0) Casts
    cast_f32_bf16<<<(M * EMBD) / (256 * 8), 256, 0, stream>>>(x, xbf);
    {
        dim3 g(QKV3 / 64, EMBD / 64);
        transpose_cast_bf16<<<g, 256, 0, stream>>>(W_qkv, Wqkv_t, EMBD, QKV3);
    }
    {
        dim3 g(EMBD / 64, EMBD / 64);
        transpose_cast_bf16<<<g, 256, 0, stream>>>(W_out, Wout_t, EMBD, EMBD);
    }
    // 1) QKV projection (bf16 out; Q columns pre-scaled by 0.125)
    {
        dim3 grid(QKV3 / 128, M / 128);
        gemm_bt_mfma<true><<<grid, 256, 0, stream>>>(xbf, Wqkv_t, b_qkv, qkv, M, QKV3, EMBD, EMBD);
    }
    // 1b) Pre-transpose V to [bh][d][k]
    {
        dim3 grid(SEQ / 64, BATCH * NHEAD);
        transpose_v_bf16<<<grid, 256, 0, stream>>>(qkv, vtbuf);
    }
    // 2) K-parallel MFMA flash causal attention (32 q/block, no loop barriers)
    {
        dim3 grid(BATCH * NHEAD, SEQ / 32);
        attn_kpar_mfma<<<grid, 256, 0, stream>>>(qkv, vtbuf, attn);
    }
    // 3) Output projection (fp32 out)
    {
        dim3 grid(EMBD / 128, M / 128);
        gemm_bt_mfma<false><<<grid, 256, 0, stream>>>(attn, Wout_t, b_out, out, M, EMBD, EMBD, 0);
    }
}